// Round 8
// baseline (143886.340 us; speedup 1.0000x reference)
//
#include <hip/hip_runtime.h>
#include <cmath>

#define NBLK 256
#define NTHR 1024
#define Bv 64
#define Lv 4
#define Hv 512
#define Tv 256
#define G4 2048

// ws layout (bytes)
#define WT_OFF   0u                       // [256 blk][4 l][8 col][1024 k] f32 = 32 MB
#define HT_OFF   (33554432u)              // hT [2 par][4 l][128 k4][64 b][4] f32 = 1 MB
#define YT_OFF   (HT_OFF + 1048576u)      // yT [128][64][4] f32 = 128 KB
#define BIAS_OFF (YT_OFF + 131072u)       // biasC [4][2048] f32 = 32 KB
#define BAR_OFF  (BIAS_OFF + 32768u)      // bar8: 8 counters @ 64B stride

__device__ __forceinline__ float sigmoidf_(float x) {
    return 1.0f / (1.0f + __expf(-x));
}

// wt[bid][l][col][k]: col = 4*(hn&1)+g for hn = bid*2 + (col>>2);
// k<512 from Wih[l][g*512+hn][k], k>=512 from Whh[l][g*512+hn][k-512]
__global__ __launch_bounds__(256) void prep_wt(const float* __restrict__ Wih,
                                               const float* __restrict__ Whh,
                                               float* __restrict__ wt) {
    int bid = blockIdx.x, tid = threadIdx.x;
    float* dst = wt + (size_t)bid * (4 * 8 * 1024);
    int k = tid * 4;
#pragma unroll
    for (int l = 0; l < 4; ++l)
#pragma unroll
        for (int col = 0; col < 8; ++col) {
            int hn = bid * 2 + (col >> 2);
            int g  = col & 3;
            const float* src = (k < 512)
                ? (Wih + ((size_t)l * G4 + g * Hv + hn) * Hv + k)
                : (Whh + ((size_t)l * G4 + g * Hv + hn) * Hv + (k - 512));
            *(float4*)(dst + (size_t)(l * 8 + col) * 1024 + k) = *(const float4*)src;
        }
}

// biasC[l][4*hn+g] = bih[l][g*512+hn] + bhh[l][g*512+hn]
__global__ void prep_bias(const float* __restrict__ bih, const float* __restrict__ bhh,
                          float* __restrict__ biasC) {
    int idx = blockIdx.x * 256 + threadIdx.x;       // 8192
    int l = idx >> 11, gi = idx & 2047;
    int hn = gi >> 2, g = gi & 3;
    biasC[idx] = bih[l * G4 + g * Hv + hn] + bhh[l * G4 + g * Hv + hn];
}

// yT[k4][b][sub] = y[b][4*k4+sub]; hT[1][l][k4][b][sub] = h0[l][b][4*k4+sub]
__global__ void prep_act(const float* __restrict__ y, const float* __restrict__ h0,
                         float* __restrict__ yT, float* __restrict__ hT) {
    int idx = blockIdx.x * 256 + threadIdx.x;
    if (idx < 32768) {
        int k4 = idx >> 8, b = (idx >> 2) & 63, sub = idx & 3;
        yT[idx] = y[b * Hv + k4 * 4 + sub];
    } else if (idx < 32768 + 131072) {
        int r2 = idx - 32768;
        int l = r2 >> 15, r = r2 & 32767;
        int k4 = r >> 8, b = (r >> 2) & 63, sub = r & 3;
        hT[(size_t)(4 + l) * 32768 + r] = h0[((size_t)l * Bv + b) * Hv + k4 * 4 + sub];
    }
}

// Persistent kernel: 256 blocks x 1024 threads, 1024 phases (t*4+l).
// Block bid owns gate-cols 8*bid..8*bid+7 (h-units 2*bid,2*bid+1), all layers.
// W slice (128 KB) lives in LDS for the whole kernel: loaded once, then read
// via wave-uniform broadcast ds_reads (zero global W traffic after prologue).
// Thread (b = tid&63, s = tid>>6): k-slice s*64..+63 of the 1024-long dot.
// h exchange via relaxed agent-scope atomics (L3-coherent), as validated R5.
__global__ __launch_bounds__(NTHR) void lstm_persist(
    const float* __restrict__ wt, const float* __restrict__ biasC,
    const float* __restrict__ yT, const float* __restrict__ c0,
    float* __restrict__ hT, float* __restrict__ out,
    int* __restrict__ bar8)
{
    const int bid = blockIdx.x;
    const int tid = threadIdx.x;
    const int b   = tid & 63;
    const int s   = __builtin_amdgcn_readfirstlane(tid >> 6);   // 0..15 wave-uniform

    __shared__ float  wlds[4 * 8 * 1024];   // 128 KB: [l][col][k]
    __shared__ float4 red[16][64];          // 16 KB reduce buffer (two passes)

    // ---- prologue: W slice -> LDS (the only global W read of the kernel) ----
    {
        const float4* src = (const float4*)(wt + (size_t)bid * 32768);
        float4* dst = (float4*)wlds;
#pragma unroll
        for (int i = 0; i < 8; ++i)
            dst[tid + i * NTHR] = src[tid + i * NTHR];
    }

    // c-state in registers of epilogue threads (tid<64, b=tid): [l][hn]
    float cc[4][2];
    if (tid < 64) {
#pragma unroll
        for (int l = 0; l < 4; ++l) {
            cc[l][0] = c0[((size_t)l * Bv + tid) * Hv + bid * 2 + 0];
            cc[l][1] = c0[((size_t)l * Bv + tid) * Hv + bid * 2 + 1];
        }
    }
    __syncthreads();

    for (int p = 0; p < Tv * Lv; ++p) {
        const int t = p >> 2, l = p & 3;
        const int par = t & 1, ppar = par ^ 1;

        const float* xa = (l == 0)
            ? (t == 0 ? yT : hT + (size_t)(ppar * 4 + 3) * 32768)
            : hT + (size_t)(par * 4 + (l - 1)) * 32768;
        const float* ha = hT + (size_t)(ppar * 4 + l) * 32768;

        // 64 activation floats for batch b, k-slice s*64.. (L3-coherent loads)
        const float* act = (s < 8) ? xa : ha;
        const unsigned long long* aq =
            (const unsigned long long*)act + (size_t)(s & 7) * 2048 + b * 2;

        float av[64];
#pragma unroll
        for (int j = 0; j < 16; ++j) {
            unsigned long long lo = __hip_atomic_load(aq + (size_t)j * 128,
                                      __ATOMIC_RELAXED, __HIP_MEMORY_SCOPE_AGENT);
            unsigned long long hi = __hip_atomic_load(aq + (size_t)j * 128 + 1,
                                      __ATOMIC_RELAXED, __HIP_MEMORY_SCOPE_AGENT);
            av[4 * j + 0] = __uint_as_float((unsigned)(lo & 0xffffffffu));
            av[4 * j + 1] = __uint_as_float((unsigned)(lo >> 32));
            av[4 * j + 2] = __uint_as_float((unsigned)(hi & 0xffffffffu));
            av[4 * j + 3] = __uint_as_float((unsigned)(hi >> 32));
        }

        // W from LDS, wave-uniform address -> broadcast, conflict-free
        const float* wl = wlds + l * 8192 + s * 64;
        float acc[8];
#pragma unroll
        for (int col = 0; col < 8; ++col) {
            const float* wp = wl + col * 1024;
            float sum = 0.f;
#pragma unroll
            for (int k = 0; k < 64; ++k)
                sum = fmaf(wp[k], av[k], sum);
            acc[col] = sum;
        }

        // ---- two-pass gate reduce + epilogue (hn = 0, then hn = 1) ----
#pragma unroll
        for (int hn = 0; hn < 2; ++hn) {
            red[s][b] = make_float4(acc[4 * hn + 0], acc[4 * hn + 1],
                                    acc[4 * hn + 2], acc[4 * hn + 3]);
            __syncthreads();
            if (tid < 64) {
                float gx = 0.f, gy = 0.f, gz = 0.f, gw = 0.f;
#pragma unroll
                for (int ss = 0; ss < 16; ++ss) {
                    float4 r = red[ss][tid];
                    gx += r.x; gy += r.y; gz += r.z; gw += r.w;
                }
                float4 bb4 = *(const float4*)(biasC + l * G4 + bid * 8 + hn * 4);
                float ig = sigmoidf_(gx + bb4.x);
                float fg = sigmoidf_(gy + bb4.y);
                float gv = tanhf(gz + bb4.z);
                float og = sigmoidf_(gw + bb4.w);

                float cn = fg * cc[l][hn] + ig * gv;
                cc[l][hn] = cn;
                float hv = og * tanhf(cn);

                int n = bid * 2 + hn;
                __hip_atomic_store(
                    &hT[(size_t)(par * 4 + l) * 32768 + ((n >> 2) * 64 + tid) * 4 + (n & 3)],
                    hv, __ATOMIC_RELAXED, __HIP_MEMORY_SCOPE_AGENT);
                if (l == Lv - 1)
                    out[((size_t)tid * Tv + t) * Hv + n] = hv;
            }
            __syncthreads();
        }

        // ---- inter-block barrier (monotonic, spread counters, no invalidates)
        if (tid == 0)
            __hip_atomic_fetch_add(&bar8[(bid & 7) * 16], 1,
                                   __ATOMIC_RELEASE, __HIP_MEMORY_SCOPE_AGENT);
        if (tid < 8) {
            const int target = 32 * (p + 1);
            while (__hip_atomic_load(&bar8[tid * 16], __ATOMIC_RELAXED,
                                     __HIP_MEMORY_SCOPE_AGENT) < target) {}
        }
        __syncthreads();
    }
}

extern "C" void kernel_launch(void* const* d_in, const int* in_sizes, int n_in,
                              void* d_out, int out_size, void* d_ws, size_t ws_size,
                              hipStream_t stream)
{
    const float* y   = (const float*)d_in[0];
    const float* h0  = (const float*)d_in[1];
    const float* c0  = (const float*)d_in[2];
    const float* Wih = (const float*)d_in[3];
    const float* Whh = (const float*)d_in[4];
    const float* bih = (const float*)d_in[5];
    const float* bhh = (const float*)d_in[6];
    float* out = (float*)d_out;

    char* ws = (char*)d_ws;
    float* wt    = (float*)(ws + WT_OFF);
    float* hT    = (float*)(ws + HT_OFF);
    float* yT    = (float*)(ws + YT_OFF);
    float* biasC = (float*)(ws + BIAS_OFF);
    int*   bar8  = (int*)(ws + BAR_OFF);

    hipMemsetAsync(ws + BAR_OFF, 0, 1024, stream);

    prep_wt<<<NBLK, 256, 0, stream>>>(Wih, Whh, wt);
    prep_bias<<<32, 256, 0, stream>>>(bih, bhh, biasC);
    prep_act<<<(32768 + 131072) / 256, 256, 0, stream>>>(y, h0, yT, hT);

    lstm_persist<<<NBLK, NTHR, 0, stream>>>(wt, biasC, yT, c0, hT, out, bar8);
}

// Round 9
// 143158.435 us; speedup vs baseline: 1.0051x; 1.0051x over previous
//
#include <hip/hip_runtime.h>
#include <cmath>

#define NBLK 256
#define NTHR 1024
#define Bv 64
#define Lv 4
#define Hv 512
#define Tv 256
#define G4 2048

// ws layout (bytes)
#define WT_OFF   0u                       // [256 blk][4 l][8 col][1024 k] f32 = 32 MB
#define HT_OFF   (33554432u)              // hT [2 par][4 l][128 k4][64 b][4] f32 = 1 MB
#define YT_OFF   (HT_OFF + 1048576u)      // yT [128][64][4] f32 = 128 KB
#define BIAS_OFF (YT_OFF + 131072u)       // biasC [4][2048] f32 = 32 KB
#define BAR_OFF  (BIAS_OFF + 32768u)      // bar8: 8 counters @ 64B stride

__device__ __forceinline__ float sigmoidf_(float x) {
    return 1.0f / (1.0f + __expf(-x));
}

// wt[bid][l][col][k]: col = 4*(hn&1)+g for hn = bid*2 + (col>>2);
// k<512 from Wih[l][g*512+hn][k], k>=512 from Whh[l][g*512+hn][k-512]
__global__ __launch_bounds__(256) void prep_wt(const float* __restrict__ Wih,
                                               const float* __restrict__ Whh,
                                               float* __restrict__ wt) {
    int bid = blockIdx.x, tid = threadIdx.x;
    float* dst = wt + (size_t)bid * (4 * 8 * 1024);
    int k = tid * 4;
#pragma unroll
    for (int l = 0; l < 4; ++l)
#pragma unroll
        for (int col = 0; col < 8; ++col) {
            int hn = bid * 2 + (col >> 2);
            int g  = col & 3;
            const float* src = (k < 512)
                ? (Wih + ((size_t)l * G4 + g * Hv + hn) * Hv + k)
                : (Whh + ((size_t)l * G4 + g * Hv + hn) * Hv + (k - 512));
            *(float4*)(dst + (size_t)(l * 8 + col) * 1024 + k) = *(const float4*)src;
        }
}

// biasC[l][4*hn+g] = bih[l][g*512+hn] + bhh[l][g*512+hn]
__global__ void prep_bias(const float* __restrict__ bih, const float* __restrict__ bhh,
                          float* __restrict__ biasC) {
    int idx = blockIdx.x * 256 + threadIdx.x;       // 8192
    int l = idx >> 11, gi = idx & 2047;
    int hn = gi >> 2, g = gi & 3;
    biasC[idx] = bih[l * G4 + g * Hv + hn] + bhh[l * G4 + g * Hv + hn];
}

// yT[k4][b][sub] = y[b][4*k4+sub]; hT[1][l][k4][b][sub] = h0[l][b][4*k4+sub]
__global__ void prep_act(const float* __restrict__ y, const float* __restrict__ h0,
                         float* __restrict__ yT, float* __restrict__ hT) {
    int idx = blockIdx.x * 256 + threadIdx.x;
    if (idx < 32768) {
        int k4 = idx >> 8, b = (idx >> 2) & 63, sub = idx & 3;
        yT[idx] = y[b * Hv + k4 * 4 + sub];
    } else if (idx < 32768 + 131072) {
        int r2 = idx - 32768;
        int l = r2 >> 15, r = r2 & 32767;
        int k4 = r >> 8, b = (r >> 2) & 63, sub = r & 3;
        hT[(size_t)(4 + l) * 32768 + r] = h0[((size_t)l * Bv + b) * Hv + k4 * 4 + sub];
    }
}

// Persistent kernel: 256 blocks x 1024 threads, 1024 phases (t*4+l).
// Block bid owns gate-cols 8*bid..8*bid+7 (h-units 2*bid,2*bid+1), all layers.
// W slice (128 KB) lives in LDS for the whole kernel: loaded once, then read
// via wave-uniform broadcast ds_reads (zero global W traffic after prologue).
// Thread (b = tid&63, s = tid>>6): k-slice s*64..+63 of the 1024-long dot.
// h exchange via relaxed agent-scope atomics (L3-coherent), as validated R5.
__global__ __launch_bounds__(NTHR) void lstm_persist(
    const float* __restrict__ wt, const float* __restrict__ biasC,
    const float* __restrict__ yT, const float* __restrict__ c0,
    float* __restrict__ hT, float* __restrict__ out,
    int* __restrict__ bar8)
{
    const int bid = blockIdx.x;
    const int tid = threadIdx.x;
    const int b   = tid & 63;
    const int s   = __builtin_amdgcn_readfirstlane(tid >> 6);   // 0..15 wave-uniform

    __shared__ float  wlds[4 * 8 * 1024];   // 128 KB: [l][col][k]
    __shared__ float4 red[16][64];          // 16 KB reduce buffer (two passes)

    // ---- prologue: W slice -> LDS (the only global W read of the kernel) ----
    {
        const float4* src = (const float4*)(wt + (size_t)bid * 32768);
        float4* dst = (float4*)wlds;
#pragma unroll
        for (int i = 0; i < 8; ++i)
            dst[tid + i * NTHR] = src[tid + i * NTHR];
    }

    // c-state in registers of epilogue threads (tid<64, b=tid): [l][hn]
    float cc[4][2];
    if (tid < 64) {
#pragma unroll
        for (int l = 0; l < 4; ++l) {
            cc[l][0] = c0[((size_t)l * Bv + tid) * Hv + bid * 2 + 0];
            cc[l][1] = c0[((size_t)l * Bv + tid) * Hv + bid * 2 + 1];
        }
    }
    __syncthreads();

    for (int p = 0; p < Tv * Lv; ++p) {
        const int t = p >> 2, l = p & 3;
        const int par = t & 1, ppar = par ^ 1;

        const float* xa = (l == 0)
            ? (t == 0 ? yT : hT + (size_t)(ppar * 4 + 3) * 32768)
            : hT + (size_t)(par * 4 + (l - 1)) * 32768;
        const float* ha = hT + (size_t)(ppar * 4 + l) * 32768;

        // 64 activation floats for batch b, k-slice s*64.. (L3-coherent loads)
        const float* act = (s < 8) ? xa : ha;
        const unsigned long long* aq =
            (const unsigned long long*)act + (size_t)(s & 7) * 2048 + b * 2;

        float av[64];
#pragma unroll
        for (int j = 0; j < 16; ++j) {
            unsigned long long lo = __hip_atomic_load(aq + (size_t)j * 128,
                                      __ATOMIC_RELAXED, __HIP_MEMORY_SCOPE_AGENT);
            unsigned long long hi = __hip_atomic_load(aq + (size_t)j * 128 + 1,
                                      __ATOMIC_RELAXED, __HIP_MEMORY_SCOPE_AGENT);
            av[4 * j + 0] = __uint_as_float((unsigned)(lo & 0xffffffffu));
            av[4 * j + 1] = __uint_as_float((unsigned)(lo >> 32));
            av[4 * j + 2] = __uint_as_float((unsigned)(hi & 0xffffffffu));
            av[4 * j + 3] = __uint_as_float((unsigned)(hi >> 32));
        }

        // W from LDS, wave-uniform address -> broadcast, conflict-free
        const float* wl = wlds + l * 8192 + s * 64;
        float acc[8];
#pragma unroll
        for (int col = 0; col < 8; ++col) {
            const float* wp = wl + col * 1024;
            float sum = 0.f;
#pragma unroll
            for (int k = 0; k < 64; ++k)
                sum = fmaf(wp[k], av[k], sum);
            acc[col] = sum;
        }

        // ---- two-pass gate reduce + epilogue (hn = 0, then hn = 1) ----
#pragma unroll
        for (int hn = 0; hn < 2; ++hn) {
            red[s][b] = make_float4(acc[4 * hn + 0], acc[4 * hn + 1],
                                    acc[4 * hn + 2], acc[4 * hn + 3]);
            __syncthreads();
            if (tid < 64) {
                float gx = 0.f, gy = 0.f, gz = 0.f, gw = 0.f;
#pragma unroll
                for (int ss = 0; ss < 16; ++ss) {
                    float4 r = red[ss][tid];
                    gx += r.x; gy += r.y; gz += r.z; gw += r.w;
                }
                float4 bb4 = *(const float4*)(biasC + l * G4 + bid * 8 + hn * 4);
                float ig = sigmoidf_(gx + bb4.x);
                float fg = sigmoidf_(gy + bb4.y);
                float gv = tanhf(gz + bb4.z);
                float og = sigmoidf_(gw + bb4.w);

                float cn = fg * cc[l][hn] + ig * gv;
                cc[l][hn] = cn;
                float hv = og * tanhf(cn);

                int n = bid * 2 + hn;
                __hip_atomic_store(
                    &hT[(size_t)(par * 4 + l) * 32768 + ((n >> 2) * 64 + tid) * 4 + (n & 3)],
                    hv, __ATOMIC_RELAXED, __HIP_MEMORY_SCOPE_AGENT);
                if (l == Lv - 1)
                    out[((size_t)tid * Tv + t) * Hv + n] = hv;
            }
            __syncthreads();
        }

        // ---- inter-block barrier (monotonic, spread counters, no invalidates)
        if (tid == 0)
            __hip_atomic_fetch_add(&bar8[(bid & 7) * 16], 1,
                                   __ATOMIC_RELEASE, __HIP_MEMORY_SCOPE_AGENT);
        if (tid < 8) {
            const int target = 32 * (p + 1);
            while (__hip_atomic_load(&bar8[tid * 16], __ATOMIC_RELAXED,
                                     __HIP_MEMORY_SCOPE_AGENT) < target) {}
        }
        __syncthreads();
    }
}

extern "C" void kernel_launch(void* const* d_in, const int* in_sizes, int n_in,
                              void* d_out, int out_size, void* d_ws, size_t ws_size,
                              hipStream_t stream)
{
    const float* y   = (const float*)d_in[0];
    const float* h0  = (const float*)d_in[1];
    const float* c0  = (const float*)d_in[2];
    const float* Wih = (const float*)d_in[3];
    const float* Whh = (const float*)d_in[4];
    const float* bih = (const float*)d_in[5];
    const float* bhh = (const float*)d_in[6];
    float* out = (float*)d_out;

    char* ws = (char*)d_ws;
    float* wt    = (float*)(ws + WT_OFF);
    float* hT    = (float*)(ws + HT_OFF);
    float* yT    = (float*)(ws + YT_OFF);
    float* biasC = (float*)(ws + BIAS_OFF);
    int*   bar8  = (int*)(ws + BAR_OFF);

    hipMemsetAsync(ws + BAR_OFF, 0, 1024, stream);

    prep_wt<<<NBLK, 256, 0, stream>>>(Wih, Whh, wt);
    prep_bias<<<32, 256, 0, stream>>>(bih, bhh, biasC);
    prep_act<<<(32768 + 131072) / 256, 256, 0, stream>>>(y, h0, yT, hT);

    lstm_persist<<<NBLK, NTHR, 0, stream>>>(wt, biasC, yT, c0, hT, out, bar8);
}

// Round 10
// 139360.303 us; speedup vs baseline: 1.0325x; 1.0273x over previous
//
#include <hip/hip_runtime.h>
#include <cmath>

#define NBLK 256
#define NTHR 1024
#define Bv 64
#define Lv 4
#define Hv 512
#define Tv 256
#define G4 2048

// ws layout (bytes)
#define WT_OFF   0u                       // [256 blk][l][s][j][col][4] f32 = 32 MB
#define HT_OFF   (33554432u)              // hT [2 par][4 l][128 k4][64 b][4] f32 = 1 MB
#define YT_OFF   (HT_OFF + 1048576u)      // yT [128][64][4] f32 = 128 KB
#define BIAS_OFF (YT_OFF + 131072u)       // biasC [4][2048] f32 = 32 KB
#define BAR_OFF  (BIAS_OFF + 32768u)      // bar8: 8 counters @ 64B stride

__device__ __forceinline__ float sigmoidf_(float x) {
    return 1.0f / (1.0f + __expf(-x));
}
__device__ __forceinline__ float lo32f(unsigned long long v) {
    return __uint_as_float((unsigned)(v & 0xffffffffu));
}
__device__ __forceinline__ float hi32f(unsigned long long v) {
    return __uint_as_float((unsigned)(v >> 32));
}

// wt per block, chunk-interleaved: flat i = ((l*16+s)*16+j)*32 + col*4 + sub
//   k = s*64 + j*4 + sub ; col = 4*hnLocal + g ; hn = bid*2 + hnLocal
//   k<512 from Wih[l][g*512+hn][k], k>=512 from Whh[l][g*512+hn][k-512]
__global__ __launch_bounds__(256) void prep_wt(const float* __restrict__ Wih,
                                               const float* __restrict__ Whh,
                                               float* __restrict__ wt) {
    int bid = blockIdx.x, tid = threadIdx.x;
    float* dst = wt + (size_t)bid * 32768;
    for (int i = tid; i < 32768; i += 256) {
        int sub = i & 3;
        int col = (i >> 2) & 7;
        int j   = (i >> 5) & 15;
        int s   = (i >> 9) & 15;
        int l   = i >> 13;
        int k   = s * 64 + j * 4 + sub;
        int hn  = bid * 2 + (col >> 2);
        int g   = col & 3;
        dst[i] = (k < 512)
            ? Wih[((size_t)l * G4 + g * Hv + hn) * Hv + k]
            : Whh[((size_t)l * G4 + g * Hv + hn) * Hv + (k - 512)];
    }
}

// biasC[l][4*hn+g] = bih[l][g*512+hn] + bhh[l][g*512+hn]
__global__ void prep_bias(const float* __restrict__ bih, const float* __restrict__ bhh,
                          float* __restrict__ biasC) {
    int idx = blockIdx.x * 256 + threadIdx.x;       // 8192
    int l = idx >> 11, gi = idx & 2047;
    int hn = gi >> 2, g = gi & 3;
    biasC[idx] = bih[l * G4 + g * Hv + hn] + bhh[l * G4 + g * Hv + hn];
}

// yT[k4][b][sub] = y[b][4*k4+sub]; hT[1][l][k4][b][sub] = h0[l][b][4*k4+sub]
__global__ void prep_act(const float* __restrict__ y, const float* __restrict__ h0,
                         float* __restrict__ yT, float* __restrict__ hT) {
    int idx = blockIdx.x * 256 + threadIdx.x;
    if (idx < 32768) {
        int k4 = idx >> 8, b = (idx >> 2) & 63, sub = idx & 3;
        yT[idx] = y[b * Hv + k4 * 4 + sub];
    } else if (idx < 32768 + 131072) {
        int r2 = idx - 32768;
        int l = r2 >> 15, r = r2 & 32767;
        int k4 = r >> 8, b = (r >> 2) & 63, sub = r & 3;
        hT[(size_t)(4 + l) * 32768 + r] = h0[((size_t)l * Bv + b) * Hv + k4 * 4 + sub];
    }
}

// Persistent kernel: 256 blocks x 1024 threads, 1024 phases (t*4+l).
// Block bid owns gate-cols 8*bid..+7 (h-units 2*bid, 2*bid+1), all layers.
// W slice (128 KB) LDS-resident, chunk-interleaved so each 4-k chunk's
// 8 cols are 8 contiguous ds_read_b128 at wave-uniform (broadcast) addrs.
// Dot loop: explicit 4-chunk double-buffered act prefetch (no spill).
// h exchange via relaxed agent-scope atomics (L3-coherent, R5-validated).
__global__ __launch_bounds__(NTHR, 4) void lstm_persist(
    const float* __restrict__ wt, const float* __restrict__ biasC,
    const float* __restrict__ yT, const float* __restrict__ c0,
    float* __restrict__ hT, float* __restrict__ out,
    int* __restrict__ bar8)
{
    const int bid = blockIdx.x;
    const int tid = threadIdx.x;
    const int b   = tid & 63;
    const int s   = __builtin_amdgcn_readfirstlane(tid >> 6);   // 0..15 wave-uniform

    __shared__ float  wlds[4 * 8 * 1024];   // 128 KB: [l][s][j][col][4]
    __shared__ float4 red[16][64];          // 16 KB reduce buffer (two passes)

    // ---- prologue: W slice -> LDS (the only global W read of the kernel) ----
    {
        const float4* src = (const float4*)(wt + (size_t)bid * 32768);
        float4* dst = (float4*)wlds;
#pragma unroll
        for (int i = 0; i < 8; ++i)
            dst[tid + i * NTHR] = src[tid + i * NTHR];
    }

    // c-state in registers of epilogue threads (tid<64, b=tid): [l][hn]
    float cc[4][2];
    if (tid < 64) {
#pragma unroll
        for (int l = 0; l < 4; ++l) {
            cc[l][0] = c0[((size_t)l * Bv + tid) * Hv + bid * 2 + 0];
            cc[l][1] = c0[((size_t)l * Bv + tid) * Hv + bid * 2 + 1];
        }
    }
    __syncthreads();

    for (int p = 0; p < Tv * Lv; ++p) {
        const int t = p >> 2, l = p & 3;
        const int par = t & 1, ppar = par ^ 1;

        const float* xa = (l == 0)
            ? (t == 0 ? yT : hT + (size_t)(ppar * 4 + 3) * 32768)
            : hT + (size_t)(par * 4 + (l - 1)) * 32768;
        const float* ha = hT + (size_t)(ppar * 4 + l) * 32768;

        const float* act = (s < 8) ? xa : ha;
        // chunk j covers k' = (s&7)*64 + j*4 .. +3 -> u64 idx ((s&7)*16+j)*128 + b*2
        const unsigned long long* aq =
            (const unsigned long long*)act + (size_t)(s & 7) * 2048 + b * 2;

        const float* wl = wlds + (l * 16 + s) * 512;

        float acc[8];
#pragma unroll
        for (int c = 0; c < 8; ++c) acc[c] = 0.f;

        unsigned long long bufA[8], bufB[8];
#pragma unroll
        for (int q = 0; q < 8; ++q)
            bufA[q] = __hip_atomic_load(aq + (size_t)(q >> 1) * 128 + (q & 1),
                                        __ATOMIC_RELAXED, __HIP_MEMORY_SCOPE_AGENT);
#pragma unroll
        for (int g = 0; g < 4; ++g) {
            const unsigned long long* cur = (g & 1) ? bufB : bufA;
            unsigned long long*       nxt = (g & 1) ? bufA : bufB;
            if (g < 3) {
#pragma unroll
                for (int q = 0; q < 8; ++q)
                    nxt[q] = __hip_atomic_load(
                        aq + (size_t)((g + 1) * 4 + (q >> 1)) * 128 + (q & 1),
                        __ATOMIC_RELAXED, __HIP_MEMORY_SCOPE_AGENT);
            }
#pragma unroll
            for (int jj = 0; jj < 4; ++jj) {
                float a0 = lo32f(cur[jj * 2]);
                float a1 = hi32f(cur[jj * 2]);
                float a2 = lo32f(cur[jj * 2 + 1]);
                float a3 = hi32f(cur[jj * 2 + 1]);
                const float4* wq = (const float4*)(wl + (g * 4 + jj) * 32);
#pragma unroll
                for (int c = 0; c < 8; ++c) {
                    float4 w4 = wq[c];
                    acc[c] = fmaf(a0, w4.x, acc[c]);
                    acc[c] = fmaf(a1, w4.y, acc[c]);
                    acc[c] = fmaf(a2, w4.z, acc[c]);
                    acc[c] = fmaf(a3, w4.w, acc[c]);
                }
            }
        }

        // ---- two-pass gate reduce + epilogue (hn = 0, then hn = 1) ----
#pragma unroll
        for (int hn = 0; hn < 2; ++hn) {
            red[s][b] = make_float4(acc[4 * hn + 0], acc[4 * hn + 1],
                                    acc[4 * hn + 2], acc[4 * hn + 3]);
            __syncthreads();
            if (tid < 64) {
                float gx = 0.f, gy = 0.f, gz = 0.f, gw = 0.f;
#pragma unroll
                for (int ss = 0; ss < 16; ++ss) {
                    float4 r = red[ss][tid];
                    gx += r.x; gy += r.y; gz += r.z; gw += r.w;
                }
                float4 bb4 = *(const float4*)(biasC + l * G4 + bid * 8 + hn * 4);
                float ig = sigmoidf_(gx + bb4.x);
                float fg = sigmoidf_(gy + bb4.y);
                float gv = tanhf(gz + bb4.z);
                float og = sigmoidf_(gw + bb4.w);

                float cn = fg * cc[l][hn] + ig * gv;
                cc[l][hn] = cn;
                float hv = og * tanhf(cn);

                int n = bid * 2 + hn;
                __hip_atomic_store(
                    &hT[(size_t)(par * 4 + l) * 32768 + ((n >> 2) * 64 + tid) * 4 + (n & 3)],
                    hv, __ATOMIC_RELAXED, __HIP_MEMORY_SCOPE_AGENT);
                if (l == Lv - 1)
                    out[((size_t)tid * Tv + t) * Hv + n] = hv;
            }
            __syncthreads();
        }

        // ---- inter-block barrier (monotonic, spread counters, no invalidates)
        if (tid == 0)
            __hip_atomic_fetch_add(&bar8[(bid & 7) * 16], 1,
                                   __ATOMIC_RELEASE, __HIP_MEMORY_SCOPE_AGENT);
        if (tid < 8) {
            const int target = 32 * (p + 1);
            while (__hip_atomic_load(&bar8[tid * 16], __ATOMIC_RELAXED,
                                     __HIP_MEMORY_SCOPE_AGENT) < target) {}
        }
        __syncthreads();
    }
}

extern "C" void kernel_launch(void* const* d_in, const int* in_sizes, int n_in,
                              void* d_out, int out_size, void* d_ws, size_t ws_size,
                              hipStream_t stream)
{
    const float* y   = (const float*)d_in[0];
    const float* h0  = (const float*)d_in[1];
    const float* c0  = (const float*)d_in[2];
    const float* Wih = (const float*)d_in[3];
    const float* Whh = (const float*)d_in[4];
    const float* bih = (const float*)d_in[5];
    const float* bhh = (const float*)d_in[6];
    float* out = (float*)d_out;

    char* ws = (char*)d_ws;
    float* wt    = (float*)(ws + WT_OFF);
    float* hT    = (float*)(ws + HT_OFF);
    float* yT    = (float*)(ws + YT_OFF);
    float* biasC = (float*)(ws + BIAS_OFF);
    int*   bar8  = (int*)(ws + BAR_OFF);

    hipMemsetAsync(ws + BAR_OFF, 0, 1024, stream);

    prep_wt<<<NBLK, 256, 0, stream>>>(Wih, Whh, wt);
    prep_bias<<<32, 256, 0, stream>>>(bih, bhh, biasC);
    prep_act<<<(32768 + 131072) / 256, 256, 0, stream>>>(y, h0, yT, hT);

    lstm_persist<<<NBLK, NTHR, 0, stream>>>(wt, biasC, yT, c0, hT, out, bar8);
}